// Round 15
// baseline (371.802 us; speedup 1.0000x reference)
//
#include <hip/hip_runtime.h>

#define Nn 100000
#define Ne 100000
#define NNZC 1600000
#define NBLK 2048         // scatter blocks: 8/CU (R14 post-mortem: 256 was 1/CU, latency-bound)
#define CHUNK 782         // ceil(NNZC / NBLK)
#define BSH 8             // bucket = idx >> 8 (256 ids per bucket)
#define BUCKW 256
#define NBK 391           // ceil(100000/256)
#define CAPB 5120         // padded bucket capacity (mean 4096 + 16 sigma)
#define GEMM_TOTAL 1563   // 64-row tiles (R0-proven): short blocks, clean makespan
#define FCAP 4608         // fine-pass LDS pair cache (18 KB)
#define SEGW 4            // segments per wave in gather
#define NG0 6250          // gather blocks

typedef __attribute__((ext_vector_type(8))) short short8;
typedef __attribute__((ext_vector_type(4))) float floatx4;

__device__ inline unsigned short f2bf(float f) {
    union { float f; unsigned int i; } c; c.f = f;
    unsigned int i = c.i;
    return (unsigned short)((i + 0x7fffu + ((i >> 16) & 1u)) >> 16);  // RNE
}
__device__ inline unsigned int f2bf2(float lo, float hi) {  // packed RNE
    union { float f; unsigned int i; } a, b;
    a.f = lo; b.f = hi;
    const unsigned int x = (a.i + 0x7fffu + ((a.i >> 16) & 1u)) >> 16;
    const unsigned int y = (b.i + 0x7fffu + ((b.i >> 16) & 1u)) & 0xffff0000u;
    return x | y;
}

struct FineLds {                               // fine pass (21504 B)
    int cnt[BUCKW];
    int tmp[2][BUCKW];
    unsigned int cache[FCAP];
};
union GemmFineLds {                            // gemm + fine kernel (34816 B -> 4/CU)
    unsigned short wlds[128 * 136];
    FineLds f;
};

// ---- standalone padded-bucket scatter, 2048 blocks (8/CU) ----
// Two-pass LDS aggregation (R8-proven logic), chunk = 782 pairs/block (fits L1).
__global__ __launch_bounds__(256) void scatter_kernel(
        const int* __restrict__ nidx, const int* __restrict__ eidx,
        int* __restrict__ gcurN, int* __restrict__ gcurE,
        unsigned int* __restrict__ pairsN, unsigned int* __restrict__ pairsE) {
    __shared__ struct { int a[NBK]; int b[NBK]; } sm;
    const int tid = threadIdx.x;
    for (int j = tid; j < NBK; j += 256) { sm.a[j] = 0; sm.b[j] = 0; }
    __syncthreads();
    const int base = blockIdx.x * CHUNK;
    const int lim = min(base + CHUNK, NNZC);
    // pass 1: count
    for (int i = base + tid; i < lim; i += 256) {
        atomicAdd(&sm.a[nidx[i] >> BSH], 1);
        atomicAdd(&sm.b[eidx[i] >> BSH], 1);
    }
    __syncthreads();
    // reserve contiguous ranges via memory-side returning atomics
    for (int j = tid; j < NBK; j += 256) {
        sm.a[j] = atomicAdd(&gcurN[j], sm.a[j]);
        sm.b[j] = atomicAdd(&gcurE[j], sm.b[j]);
    }
    __syncthreads();
    // pass 2: place (chunk re-read is L1-hot: 6.3 KB)
    for (int i = base + tid; i < lim; i += 256) {
        const int n = nidx[i], e = eidx[i];
        const int pn = atomicAdd(&sm.a[n >> BSH], 1);
        if (pn < CAPB)
            pairsN[(size_t)(n >> BSH) * CAPB + pn] =
                ((unsigned int)e << 8) | (unsigned int)(n & 255);
        const int pe = atomicAdd(&sm.b[e >> BSH], 1);
        if (pe < CAPB)
            pairsE[(size_t)(e >> BSH) * CAPB + pe] =
                ((unsigned int)n << 8) | (unsigned int)(e & 255);
    }
}

// ---- gemm block body: h[64 rows] = bf16(x @ W), operand-swapped MFMA (R0-proven) ----
__device__ inline void gemm_block64(int gb, const float* __restrict__ x,
                                    const float* __restrict__ w,
                                    unsigned short* __restrict__ h,
                                    unsigned short* wlds, int tid) {
    const int wave = tid >> 6, lane = tid & 63;
    const int q = lane >> 4, r16 = lane & 15;

    // stage W: w[k*128+n] fp32 -> wlds[n*136+k] bf16
    for (int i = tid; i < 4096; i += 256) {
        const int k = i >> 5;
        const int n0 = (i & 31) << 2;
        const float4 wv = *(const float4*)(w + k * 128 + n0);
        wlds[(n0 + 0) * 136 + k] = f2bf(wv.x);
        wlds[(n0 + 1) * 136 + k] = f2bf(wv.y);
        wlds[(n0 + 2) * 136 + k] = f2bf(wv.z);
        wlds[(n0 + 3) * 136 + k] = f2bf(wv.w);
    }
    __syncthreads();

    const int row0 = gb * 64 + wave * 16;
    const int rrow = min(row0 + r16, Nn - 1);

    floatx4 acc[8];
#pragma unroll
    for (int jb = 0; jb < 8; ++jb) acc[jb] = (floatx4){0.f, 0.f, 0.f, 0.f};

    const float* ap = x + (size_t)rrow * 128 + q * 8;
#pragma unroll
    for (int kk = 0; kk < 4; ++kk) {
        const float4 a0 = *(const float4*)(ap + kk * 32);
        const float4 a1 = *(const float4*)(ap + kk * 32 + 4);
        union { unsigned int u[4]; short8 s; } xf;
        xf.u[0] = f2bf2(a0.x, a0.y);
        xf.u[1] = f2bf2(a0.z, a0.w);
        xf.u[2] = f2bf2(a1.x, a1.y);
        xf.u[3] = f2bf2(a1.z, a1.w);
        const unsigned short* wp = wlds + kk * 32 + q * 8;
#pragma unroll
        for (int jb = 0; jb < 8; ++jb) {
            const short8 wf = *(const short8*)(wp + (jb * 16 + r16) * 136);
            acc[jb] = __builtin_amdgcn_mfma_f32_16x16x32_bf16(wf, xf.s, acc[jb], 0, 0, 0);
        }
    }

    if (row0 + r16 < Nn) {
        unsigned short* hb = h + (size_t)(row0 + r16) * 128 + q * 4;
#pragma unroll
        for (int jb = 0; jb < 8; ++jb) {
            uint2 o;
            o.x = f2bf2(acc[jb][0], acc[jb][1]);
            o.y = f2bf2(acc[jb][2], acc[jb][3]);
            *(uint2*)(hb + jb * 16) = o;
        }
    }
}

// ---- fine block: padded bucket -> compacted CSR (offs + perm); R11-proven ----
__device__ inline void fine_block(int b, const unsigned int* __restrict__ pairs,
                                  const int* __restrict__ gcur,
                                  int* __restrict__ offs, int* __restrict__ perm,
                                  FineLds& L, int t) {
    const int cnt_b = min(gcur[b], CAPB);
    // compacted base S = sum_{j<b} fill_j
    int part = 0;
    for (int j = t; j < b; j += 256) part += min(gcur[j], CAPB);
    L.tmp[0][t] = part;
    __syncthreads();
    for (int off = 128; off > 0; off >>= 1) {
        if (t < off) L.tmp[0][t] += L.tmp[0][t + off];
        __syncthreads();
    }
    const int S = L.tmp[0][0];
    __syncthreads();

    const unsigned int* pb = pairs + (size_t)b * CAPB;
    L.cnt[t] = 0;
    __syncthreads();
    for (int i = t; i < cnt_b; i += BUCKW) {
        const unsigned int p = pb[i];
        if (i < FCAP) L.cache[i] = p;
        atomicAdd(&L.cnt[p & 255u], 1);
    }
    __syncthreads();
    int v = L.cnt[t];
    int pin = 0;
    L.tmp[0][t] = v;
    for (int off = 1; off < BUCKW; off <<= 1) {
        __syncthreads();
        int val = L.tmp[pin][t];
        if (t >= off) val += L.tmp[pin][t - off];
        L.tmp[1 - pin][t] = val;
        pin ^= 1;
    }
    __syncthreads();
    const int excl = L.tmp[pin][t] - v;
    const int id = b * BUCKW + t;
    if (id < 100000) offs[id] = S + excl;
    if (b == NBK - 1 && t == 0) offs[100000] = NNZC;
    __syncthreads();
    L.cnt[t] = excl;   // reuse as cursors (bucket-local)
    __syncthreads();
    for (int i = t; i < cnt_b; i += BUCKW) {
        const unsigned int p = (i < FCAP) ? L.cache[i] : pb[i];
        const int pos = S + atomicAdd(&L.cnt[p & 255u], 1);
        perm[pos] = (int)(p >> 8);
    }
}

// ---- fused: gemm64 (vb<1563) + fineE (1563..1953) + fineN (1954..2344) ----
// 2345 short blocks (~4/CU resident): MFMA waves co-schedule with fine's memory
// waves; no long-block makespan tail (R14 post-mortem: 391 heavy blocks = 1.5/CU).
__global__ __launch_bounds__(256) void gemmfine_kernel(
        const float* __restrict__ x, const float* __restrict__ w,
        unsigned short* __restrict__ h,
        const unsigned int* __restrict__ pairsE, const int* __restrict__ gcurE,
        int* __restrict__ offsE, int* __restrict__ permE,
        const unsigned int* __restrict__ pairsN, const int* __restrict__ gcurN,
        int* __restrict__ offsN, int* __restrict__ permN) {
    __shared__ GemmFineLds sm;
    const int tid = threadIdx.x;
    const int vb = blockIdx.x;
    if (vb < GEMM_TOTAL) {
        gemm_block64(vb, x, w, h, sm.wlds, tid);
    } else if (vb < GEMM_TOTAL + NBK) {
        fine_block(vb - GEMM_TOTAL, pairsE, gcurE, offsE, permE, sm.f, tid);
    } else {
        fine_block(vb - GEMM_TOTAL - NBK, pairsN, gcurN, offsN, permN, sm.f, tid);
    }
}

// ---- gather body: wave owns SEGW consecutive segments, flattened streaming ----
// (R1/R4/R8/R11 form — proven at the fabric-delivery floor, ~65 us.)
template <int MODE>
__device__ inline void gather_body(int gblk, const int* __restrict__ perm,
                                   const int* __restrict__ offs,
                                   const void* __restrict__ srcv,
                                   const float* __restrict__ bias,
                                   void* __restrict__ outv, int tid) {
    const int wave = tid >> 6;
    const int lane = tid & 63;
    const int e0 = __builtin_amdgcn_readfirstlane((gblk * 4 + wave) * SEGW);
    const int start = offs[e0];
    const int end = offs[e0 + SEGW];
    const unsigned int laneoff = (unsigned int)lane << 2;
    const char* src = (const char*)srcv;

    float bx = 0.f, by = 0.f;
    if (MODE == 1) {
        const float2 b = ((const float2*)bias)[lane];
        bx = b.x; by = b.y;
    }

    float ax = 0.f, ay = 0.f;
    int e = e0;
    int seg_start = start;
    int nb = offs[e0 + 1];

    auto flush = [&](int deg) {
        const float sinv = deg ? 1.f / (float)deg : 0.f;
        if (MODE == 0) {
            *(unsigned int*)((char*)outv + (((unsigned int)e << 8) | laneoff)) =
                f2bf2(ax * sinv, ay * sinv);
        } else {
            float2 o;
            o.x = ax * sinv + bx;
            o.y = ay * sinv + by;
            *(float2*)((char*)outv + (((unsigned int)e << 9) | (laneoff << 1))) = o;
        }
        ax = 0.f; ay = 0.f;
        ++e;
    };

    int myv = 0;
    for (int i = start; i < end; i += 8) {
        const int t = (i - start) & 63;
        if (t == 0) myv = perm[min(i + lane, NNZC - 1)];
        const int m = min(end - i, 8);
        unsigned int a[8], u[8];
#pragma unroll
        for (int j = 0; j < 8; ++j)
            a[j] = ((unsigned int)__shfl(myv, t + (j < m ? j : m - 1), 64) << 8) | laneoff;
#pragma unroll
        for (int j = 0; j < 8; ++j) u[j] = *(const unsigned int*)(src + a[j]);
#pragma unroll
        for (int j = 0; j < 8; ++j) {
            if (j < m) {  // wave-uniform
                while (i + j == nb) {  // segment boundary (handles empty segments)
                    flush(nb - seg_start);
                    seg_start = nb;
                    nb = offs[e + 1];
                }
                ax += __uint_as_float(u[j] << 16);
                ay += __uint_as_float(u[j] & 0xffff0000u);
            }
        }
    }
    while (e < e0 + SEGW) {
        flush(end - seg_start);
        seg_start = end;
    }
}

// ---- gather<0>: nodes -> edges (h -> ef) ----
__global__ __launch_bounds__(256) void gather_n2e_kernel(
        const int* __restrict__ permE, const int* __restrict__ offsE,
        const unsigned short* __restrict__ h, unsigned short* __restrict__ ef) {
    gather_body<0>(blockIdx.x, permE, offsE, h, nullptr, ef, threadIdx.x);
}

// ---- gather<1>: edges -> nodes, final output ----
__global__ __launch_bounds__(256) void gather_e2n_kernel(
        const int* __restrict__ permN, const int* __restrict__ offsN,
        const unsigned short* __restrict__ ef, const float* __restrict__ bias,
        float* __restrict__ out) {
    gather_body<1>(blockIdx.x, permN, offsN, ef, bias, out, threadIdx.x);
}

extern "C" void kernel_launch(void* const* d_in, const int* in_sizes, int n_in,
                              void* d_out, int out_size, void* d_ws, size_t ws_size,
                              hipStream_t stream) {
    const float* x = (const float*)d_in[0];
    const float* w = (const float*)d_in[1];
    const float* bias = (const float*)d_in[2];
    const int* hei = (const int*)d_in[3];
    const int* nidx = hei;            // row 0: node indices
    const int* eidx = hei + NNZC;     // row 1: edge indices
    float* out = (float*)d_out;

    // ---- carve workspace (256B-aligned chunks), ~81 MB ----
    char* p = (char*)d_ws;
    unsigned short* h = (unsigned short*)p;  p += (size_t)Nn * 128 * 2;      // 25.6 MB
    unsigned short* ef = (unsigned short*)p; p += (size_t)Ne * 128 * 2;      // 25.6 MB
    int* gcurN = (int*)p;                    p += NBK * 4 + 192;             // bucket fills
    int* gcurE = (int*)p;                    p += NBK * 4 + 192;
    int* offsN = (int*)p;                    p += 400128;                    // 100001 ints
    int* offsE = (int*)p;                    p += 400128;
    int* permN = (int*)p;                    p += (size_t)NNZC * 4;          // 6.4 MB
    int* permE = (int*)p;                    p += (size_t)NNZC * 4;          // 6.4 MB
    unsigned int* pairsN = (unsigned int*)p; p += (size_t)NBK * CAPB * 4;    // 8.0 MB padded
    unsigned int* pairsE = (unsigned int*)p; p += (size_t)NBK * CAPB * 4;    // 8.0 MB padded

    // zero the bucket-fill cursors (contiguous pair of arrays)
    hipMemsetAsync(gcurN, 0, 2 * (NBK * 4 + 192), stream);

    // ---- 4-kernel pipeline, every stage occupancy-healthy ----
    scatter_kernel<<<NBLK, 256, 0, stream>>>(nidx, eidx, gcurN, gcurE, pairsN, pairsE);
    gemmfine_kernel<<<GEMM_TOTAL + 2 * NBK, 256, 0, stream>>>(x, w, h,
                                                              pairsE, gcurE, offsE, permE,
                                                              pairsN, gcurN, offsN, permN);
    gather_n2e_kernel<<<NG0, 256, 0, stream>>>(permE, offsE, h, ef);
    gather_e2n_kernel<<<NG0, 256, 0, stream>>>(permN, offsN, ef, bias, out);
}